// Round 2
// baseline (241.591 us; speedup 1.0000x reference)
//
#include <hip/hip_runtime.h>
#include <hip/hip_bf16.h>

// Problem constants
#define B_    8
#define CIN   128
#define H_    64
#define W_    64
#define COUT  128
#define K_    16
#define HO    61
#define WO    61
#define HW_   (HO * WO)          // 3721

typedef short bf16x8 __attribute__((ext_vector_type(8)));
typedef float f32x4  __attribute__((ext_vector_type(4)));
typedef float f32x2u __attribute__((ext_vector_type(2), aligned(4)));

// Fragment-major repacked weight (bf16), pre-flipped (transposed-conv k' = 15-k):
//   A2[((blk*64 + it)*64 + lane)*8 + j] = w[o][c][15-k]
//   o = blk*16 + (lane&15);  c = 2*it + ((lane>>4)>>1);  k = ((lane>>4)&1)*8 + j
// A wave's per-(blk,it) fragment load is then a fully coalesced 1 KB stream:
//   addr = base + blk*64KB + it*1KB + lane*16B.
__global__ __launch_bounds__(256) void prep_weight(const float* __restrict__ w,
                                                   __hip_bfloat16* __restrict__ A2) {
    int gid  = blockIdx.x * 256 + threadIdx.x;     // 32768 threads total
    int lane = gid & 63;
    int it   = (gid >> 6) & 63;
    int blk  = gid >> 12;
    int o    = blk * 16 + (lane & 15);
    int quad = lane >> 4;
    int c    = 2 * it + (quad >> 1);
    int k0   = (quad & 1) * 8;
    const float* src = w + ((size_t)(o << 7) + c) * 16;
    __hip_bfloat16* dst = A2 + (size_t)gid * 8;
    #pragma unroll
    for (int j = 0; j < 8; ++j)
        dst[j] = __float2bfloat16(src[15 - (k0 + j)]);
}

// Direct-gather deform conv: one wave owns a 16-pixel x 128-cout tile.
// B-fragments are built IN REGISTERS from the L2-resident input (no LDS, no
// __syncthreads anywhere): MFMA 16x16x32 B-layout (verified) needs lane l to
// hold kk = it*32 + (l>>4)*8 + j for pixel l&15 -> 8 fixed taps of one channel.
// 4 independent waves/block share the same A2 stream via L1; a raw (drain-free)
// s_barrier every 2 steps keeps them phase-locked for that reuse.
__global__ __launch_bounds__(256, 2) void deform_direct(
        const float* __restrict__ inp, const float* __restrict__ off,
        const float* __restrict__ msk, const __hip_bfloat16* __restrict__ A2,
        const float* __restrict__ bias, float* __restrict__ out) {

    const int lane  = threadIdx.x & 63;
    const int wv    = threadIdx.x >> 6;
    const int p     = lane & 15;          // pixel within tile == MFMA col
    const int quad  = lane >> 4;
    const int k0    = (quad & 1) * 8;     // this lane's 8-tap half
    const int chalf = quad >> 1;          // channel parity within a 32-kk step

    // tile id: waves of a block are 488 apart -> same (tile&7) -> same batch,
    // preserving batch<->XCD L2 pinning (488 % 8 == 0).
    const int tile = blockIdx.x + wv * 488;
    const int b    = tile & 7;
    const int g    = tile >> 3;
    const int ho   = g >> 2;
    const int wt   = (g & 3) << 4;
    const int wo   = wt + p;
    const bool pvalid = (wo < WO);
    const int wo_c = pvalid ? wo : (WO - 1);
    const int r    = ho * WO + wo_c;

    // ---- per-tap bilinear params for taps k = k0..k0+7 (exact border math,
    //      identical to the verified fallback path) ----
    float w00[8], w01[8], w10[8], w11[8];
    int   vo0[8], vo1[8];                 // float offsets within a 2-plane pair
    const size_t offb = (size_t)b * (2 * K_ * HW_);
    const size_t mskb = (size_t)b * (K_ * HW_);
    #pragma unroll
    for (int j = 0; j < 8; ++j) {
        const int k  = k0 + j;
        const int ki = k >> 2, kj = k & 3;
        float dy = off[offb + (size_t)(2 * k)     * HW_ + r];
        float dx = off[offb + (size_t)(2 * k + 1) * HW_ + r];
        float mm = msk[mskb + (size_t)k * HW_ + r];
        if (!pvalid) mm = 0.0f;

        float y   = dy + (float)(ki + ho);
        float x   = dx + (float)(kj + wo_c);
        float y0f = floorf(y), x0f = floorf(x);
        float wy  = y - y0f,   wx  = x - x0f;
        int y0 = (int)y0f, x0 = (int)x0f;
        int y1 = y0 + 1,   x1 = x0 + 1;

        float wy0v = (1.0f - wy) * ((y0 >= 0 && y0 < H_) ? mm : 0.0f);
        float wy1v = wy          * ((y1 >= 0 && y1 < H_) ? mm : 0.0f);
        int cy0 = min(max(y0, 0), H_ - 1), cy1 = min(max(y1, 0), H_ - 1);

        float wx0v = (1.0f - wx) * ((x0 >= 0 && x0 < W_) ? 1.0f : 0.0f);
        float wx1v = wx          * ((x1 >= 0 && x1 < W_) ? 1.0f : 0.0f);
        int xb = min(max(x0, 0), W_ - 2);
        int tsh = x0 - xb;                // -1,0,1 (else both x-weights are 0)
        float a0 = (tsh == 0) ? wx0v : ((tsh == -1) ? wx1v : 0.0f);
        float a1 = (tsh == 0) ? wx1v : ((tsh ==  1) ? wx0v : 0.0f);

        w00[j] = wy0v * a0;  w01[j] = wy0v * a1;
        w10[j] = wy1v * a0;  w11[j] = wy1v * a1;
        vo0[j] = (chalf << 12) + cy0 * W_ + xb;   // loads always in-plane
        vo1[j] = (chalf << 12) + cy1 * W_ + xb;
    }

    const float* pinb = inp + (size_t)b * (CIN * H_ * W_);
    const __hip_bfloat16* pa = A2 + (size_t)lane * 8;

    f32x4 acc[8] = {};                    // 128 couts = 8 row-blocks of 16

    // even/odd named double buffers (rule #20: all indices compile-time)
    f32x2u rA0[8], rA1[8]; bf16x8 avA[8];
    f32x2u rB0[8], rB1[8]; bf16x8 avB[8];

    auto stage = [&](int it, f32x2u (&r0)[8], f32x2u (&r1)[8], bf16x8 (&av)[8]) {
        const float* cp = pinb + ((size_t)it << 13);      // it*2 channel planes
        #pragma unroll
        for (int j = 0; j < 8; ++j) {
            r0[j] = *(const f32x2u*)(const void*)(cp + vo0[j]);
            r1[j] = *(const f32x2u*)(const void*)(cp + vo1[j]);
        }
        const __hip_bfloat16* ap = pa + ((size_t)it << 9);
        #pragma unroll
        for (int blk = 0; blk < 8; ++blk)
            av[blk] = *(const bf16x8*)(const void*)(ap + ((size_t)blk << 15));
    };

    auto consume = [&](f32x2u (&r0)[8], f32x2u (&r1)[8], bf16x8 (&av)[8]) {
        bf16x8 bb;
        #pragma unroll
        for (int j = 0; j < 8; ++j) {
            float s = w00[j] * r0[j][0] + w01[j] * r0[j][1]
                    + w10[j] * r1[j][0] + w11[j] * r1[j][1];
            __hip_bfloat16 h = __float2bfloat16(s);
            bb[j] = *reinterpret_cast<const short*>(&h);
        }
        #pragma unroll
        for (int blk = 0; blk < 8; ++blk)
            acc[blk] = __builtin_amdgcn_mfma_f32_16x16x32_bf16(av[blk], bb, acc[blk], 0, 0, 0);
    };

    stage(0, rA0, rA1, avA);
    #pragma unroll 1
    for (int it = 0; it < 64; it += 2) {
        __builtin_amdgcn_s_barrier();     // raw sync, no waitcnt drain: keeps
                                          // the 4 waves' A-streams L1-coincident
        stage(it + 1, rB0, rB1, avB);
        consume(rA0, rA1, avA);
        if (it + 2 < 64) stage(it + 2, rA0, rA1, avA);
        consume(rB0, rB1, avB);
    }

    // ---- epilogue: C/D col = lane&15 (pixel), row = quad*4 + jj (cout) ----
    if (pvalid) {
        const size_t outb = (size_t)b * (COUT * HW_) + r;
        #pragma unroll
        for (int blk = 0; blk < 8; ++blk) {
            #pragma unroll
            for (int jj = 0; jj < 4; ++jj) {
                int o = blk * 16 + quad * 4 + jj;
                out[outb + (size_t)o * HW_] = acc[blk][jj] + bias[o];
            }
        }
    }
}

extern "C" void kernel_launch(void* const* d_in, const int* in_sizes, int n_in,
                              void* d_out, int out_size, void* d_ws, size_t ws_size,
                              hipStream_t stream) {
    const float* inp  = (const float*)d_in[0];
    const float* off  = (const float*)d_in[1];
    const float* msk  = (const float*)d_in[2];
    const float* wgt  = (const float*)d_in[3];
    const float* bias = (const float*)d_in[4];
    float* out = (float*)d_out;

    __hip_bfloat16* A2 = (__hip_bfloat16*)d_ws;   // 512 KB

    prep_weight<<<128, 256, 0, stream>>>(wgt, A2);

    // 488 blocks x 4 waves; each wave owns one 16-pixel x 128-cout tile
    deform_direct<<<488, 256, 0, stream>>>(inp, off, msk, A2, bias, out);
}

// Round 4
// 173.584 us; speedup vs baseline: 1.3918x; 1.3918x over previous
//
#include <hip/hip_runtime.h>
#include <hip/hip_bf16.h>

// Problem constants
#define B_    8
#define CIN   128
#define H_    64
#define W_    64
#define COUT  128
#define K_    16
#define HO    61
#define WO    61
#define HW_   (HO * WO)          // 3721

typedef short bf16x8 __attribute__((ext_vector_type(8)));
typedef float f32x4  __attribute__((ext_vector_type(4)));
typedef float f32x4u __attribute__((ext_vector_type(4), aligned(4)));
typedef float f32x4a __attribute__((ext_vector_type(4), aligned(16)));

// ---------------------------------------------------------------------------
// Transpose input [b][c][y][x] (f32) -> T[b][y*64+x][c] (f32, channel-last).
// 2 MB/batch -> XCD-L2 resident under the batch<->XCD block pinning.
__global__ __launch_bounds__(256) void transpose_in(const float* __restrict__ inp,
                                                    float* __restrict__ T) {
    __shared__ float ld[64][129];          // pad 129: conflict-free both phases
    const int t  = threadIdx.x;
    const int b  = blockIdx.x >> 6;
    const int sb = (blockIdx.x & 63) << 6; // 64-spatial slab
    const float* src = inp + ((size_t)b << 19);
    #pragma unroll
    for (int i = 0; i < 8; ++i) {
        int j  = i * 256 + t;
        int c  = j >> 4;
        int s4 = (j & 15) << 2;
        f32x4u v = *(const f32x4u*)(const void*)(src + ((size_t)c << 12) + sb + s4);
        #pragma unroll
        for (int q = 0; q < 4; ++q) ld[s4 + q][c] = v[q];
    }
    __syncthreads();
    float* dst = T + (((size_t)b << 12) + sb) * 128;
    #pragma unroll
    for (int i = 0; i < 8; ++i) {
        int j  = i * 256 + t;
        int s  = j >> 5;
        int c4 = (j & 31) << 2;
        f32x4u v;
        #pragma unroll
        for (int q = 0; q < 4; ++q) v[q] = ld[s][c4 + q];
        *(f32x4u*)(void*)(dst + (size_t)s * 128 + c4) = v;
    }
}

// ---------------------------------------------------------------------------
// Fragment-major weight repack (bf16), pre-flipped, kk = k*128 + c (tap-major):
//   A2[((blk*64 + it)*64 + lane)*8 + j] = w[o][c][15-k]
//   o = blk*16 + (lane&15); kk = it*32 + (lane>>4)*8 + j; k = kk>>7; c = kk&127
// Wave fragment load = coalesced 1 KB stream.
__global__ __launch_bounds__(256) void prep_weight(const float* __restrict__ w,
                                                   __hip_bfloat16* __restrict__ A2) {
    int gid  = blockIdx.x * 256 + threadIdx.x;   // 32768 threads
    int lane = gid & 63;
    int it   = (gid >> 6) & 63;
    int blk  = gid >> 12;
    int o    = blk * 16 + (lane & 15);
    int kk   = it * 32 + (lane >> 4) * 8;        // j-base; never crosses c=128
    int k    = kk >> 7;
    int c0   = kk & 127;
    const float* src = w + (((size_t)(o << 7) + c0) << 4) + (15 - k);
    __hip_bfloat16* dst = A2 + (size_t)gid * 8;
    #pragma unroll
    for (int j = 0; j < 8; ++j)
        dst[j] = __float2bfloat16(src[j << 4]);  // c = c0+j, same k
}

// ---------------------------------------------------------------------------
// Main: block = 16 pixels x 128 couts, 4 waves.  Coalesced channel-last gather
// (unit = 1 tap x 32 ch x 16 pixels; lanes = 16 pairs x 4 ch-lanes, dwordx4
// segments of 128 B per pair-corner) -> swizzled Bs ring (verified layout) ->
// verified MFMA fragment path.  9 barriers/block.
__global__ __launch_bounds__(256, 3) void deform_gather(
        const float* __restrict__ T, const float* __restrict__ off,
        const float* __restrict__ msk, const __hip_bfloat16* __restrict__ A2,
        const float* __restrict__ bias, float* __restrict__ out) {

    __shared__ __align__(16) __hip_bfloat16 Bs[2][16 * 256];  // 2 x 8 KB
    __shared__ float pw[4][256];                              // b00,b01,b10,b11
    __shared__ int   pb[2][256];                              // T elem offsets

    const int t   = threadIdx.x;
    const int bid = blockIdx.x;
    const int b   = bid & 7;               // batch<->XCD pinning
    const int g   = bid >> 3;
    const int ho  = g >> 2;
    const int wt  = (g & 3) << 4;

    // ---- phase 0: exact per-(pixel,tap) bilinear params -> LDS ----
    {
        const int p  = t & 15;
        const int k  = t >> 4;
        const int wo = wt + p;
        const bool pvalid = (wo < WO);
        const int wo_c = pvalid ? wo : (WO - 1);
        const int r    = ho * WO + wo_c;
        const int ki = k >> 2, kj = k & 3;
        const size_t offb = (size_t)b * (2 * K_ * HW_);
        float dy = off[offb + (size_t)(2 * k)     * HW_ + r];
        float dx = off[offb + (size_t)(2 * k + 1) * HW_ + r];
        float mm = msk[(size_t)b * (K_ * HW_) + (size_t)k * HW_ + r];
        if (!pvalid) mm = 0.0f;

        float y   = dy + (float)(ki + ho);
        float x   = dx + (float)(kj + wo_c);
        float y0f = floorf(y), x0f = floorf(x);
        float wy  = y - y0f,   wx  = x - x0f;
        int y0 = (int)y0f, x0 = (int)x0f;
        int y1 = y0 + 1,   x1 = x0 + 1;

        float wy0v = (1.0f - wy) * ((y0 >= 0 && y0 < H_) ? mm : 0.0f);
        float wy1v = wy          * ((y1 >= 0 && y1 < H_) ? mm : 0.0f);
        int cy0 = min(max(y0, 0), H_ - 1), cy1 = min(max(y1, 0), H_ - 1);

        float wx0v = (1.0f - wx) * ((x0 >= 0 && x0 < W_) ? 1.0f : 0.0f);
        float wx1v = wx          * ((x1 >= 0 && x1 < W_) ? 1.0f : 0.0f);
        int xb = min(max(x0, 0), W_ - 2);
        int tsh = x0 - xb;                 // -1,0,1 (else both x-weights 0)
        float a0 = (tsh == 0) ? wx0v : ((tsh == -1) ? wx1v : 0.0f);
        float a1 = (tsh == 0) ? wx1v : ((tsh ==  1) ? wx0v : 0.0f);

        pw[0][t] = wy0v * a0;  pw[1][t] = wy0v * a1;
        pw[2][t] = wy1v * a0;  pw[3][t] = wy1v * a1;
        pb[0][t] = (cy0 * W_ + xb) << 7;   // *128 channels
        pb[1][t] = (cy1 * W_ + xb) << 7;
    }
    __syncthreads();

    const int lane = t & 63;
    const int wv   = t >> 6;
    const int p_g  = lane >> 2;            // gather pixel (16 pairs/wave)
    const int cg_l = (lane & 3) << 3;      // 8-ch sub-slice within 32-group
    const int mrow = lane & 15;            // MFMA pixel col
    const int quad = lane >> 4;
    const float* Tb = T + ((size_t)b << 19);
    const int u0 = wv, u1 = wv + 4;        // this wave's 2 units per half
    const int blk0 = 2 * wv, blk1 = 2 * wv + 1;

    f32x4 acc0 = {0.f, 0.f, 0.f, 0.f};
    f32x4 acc1 = {0.f, 0.f, 0.f, 0.f};

    // unit gather: 8 coalesced dwordx4 (4 corners x 8 ch), params from LDS.
    // Canonical corner order: vv[2*c+0]=corner c ch-lo, vv[2*c+1]=corner c ch-hi
    // with corners 0..3 = (y0,x0),(y0,x1),(y1,x0),(y1,x1).
    auto uget = [&](int u, int h, f32x4a* vv, float* wts, int& swz) {
        const int tap  = 2 * h + (u >> 2);
        const int pair = (tap << 4) + p_g;
        wts[0] = pw[0][pair]; wts[1] = pw[1][pair];
        wts[2] = pw[2][pair]; wts[3] = pw[3][pair];
        const int cb = ((u & 3) << 5) + cg_l;
        const float* p0 = Tb + pb[0][pair] + cb;
        const float* p1 = Tb + pb[1][pair] + cb;
        vv[0] = *(const f32x4a*)(const void*)(p0);         // (y0,x0) lo
        vv[1] = *(const f32x4a*)(const void*)(p0 + 4);     // (y0,x0) hi
        vv[2] = *(const f32x4a*)(const void*)(p0 + 128);   // (y0,x1) lo
        vv[3] = *(const f32x4a*)(const void*)(p0 + 132);   // (y0,x1) hi
        vv[4] = *(const f32x4a*)(const void*)(p1);         // (y1,x0) lo
        vv[5] = *(const f32x4a*)(const void*)(p1 + 4);     // (y1,x0) hi
        vv[6] = *(const f32x4a*)(const void*)(p1 + 128);   // (y1,x1) lo
        vv[7] = *(const f32x4a*)(const void*)(p1 + 132);   // (y1,x1) hi
        const int kkl = ((u >> 2) << 7) + cb;              // local kk base
        swz = (p_g << 8) + ((kkl + (p_g << 3)) & 255);
    };

    // combine -> bf16x8 -> one ds_write_b128 into swizzled Bs ring
    auto ucombine = [&](const f32x4a* vv, const float* wts, int swz, int hb) {
        bf16x8 bb;
        #pragma unroll
        for (int q = 0; q < 4; ++q) {      // channels cb+q (lo halves)
            float s = wts[0] * vv[0][q] + wts[1] * vv[2][q]
                    + wts[2] * vv[4][q] + wts[3] * vv[6][q];
            __hip_bfloat16 hh = __float2bfloat16(s);
            bb[q] = *reinterpret_cast<const short*>(&hh);
        }
        #pragma unroll
        for (int q = 0; q < 4; ++q) {      // channels cb+4+q (hi halves)
            float s = wts[0] * vv[1][q] + wts[1] * vv[3][q]
                    + wts[2] * vv[5][q] + wts[3] * vv[7][q];
            __hip_bfloat16 hh = __float2bfloat16(s);
            bb[4 + q] = *reinterpret_cast<const short*>(&hh);
        }
        *(bf16x8*)(void*)(&Bs[hb][swz]) = bb;
    };

    // MFMA one 256-kk half: verified fragment path, A fragment-major (coalesced)
    auto mfma_half = [&](int hp) {
        const __hip_bfloat16* a0 = A2 + ((size_t)((blk0 * 64 + hp * 8) * 64 + lane) << 3);
        const __hip_bfloat16* a1 = A2 + ((size_t)((blk1 * 64 + hp * 8) * 64 + lane) << 3);
        const int hb = hp & 1;
        #pragma unroll
        for (int s_ = 0; s_ < 8; ++s_) {
            bf16x8 av0 = *(const bf16x8*)(const void*)(a0 + ((size_t)s_ << 9));
            bf16x8 av1 = *(const bf16x8*)(const void*)(a1 + ((size_t)s_ << 9));
            const int idx = (mrow << 8) +
                            (((s_ << 5) + (quad << 3) + (mrow << 3)) & 255);
            bf16x8 bb = *(const bf16x8*)(const void*)(&Bs[hb][idx]);
            acc0 = __builtin_amdgcn_mfma_f32_16x16x32_bf16(av0, bb, acc0, 0, 0, 0);
            acc1 = __builtin_amdgcn_mfma_f32_16x16x32_bf16(av1, bb, acc1, 0, 0, 0);
        }
    };

    f32x4a vU0[8], vU1[8];
    float  wt0[4], wt1[4];
    int    sw0, sw1;

    // prologue: half 0
    uget(u0, 0, vU0, wt0, sw0);
    uget(u1, 0, vU1, wt1, sw1);
    ucombine(vU0, wt0, sw0, 0);
    ucombine(vU1, wt1, sw1, 0);
    __syncthreads();

    #pragma unroll 1
    for (int h = 1; h < 8; ++h) {
        uget(u0, h, vU0, wt0, sw0);        // issue gather loads early
        uget(u1, h, vU1, wt1, sw1);
        mfma_half(h - 1);                  // overlap with loads in flight
        ucombine(vU0, wt0, sw0, h & 1);
        ucombine(vU1, wt1, sw1, h & 1);
        __syncthreads();                   // one barrier per half
    }
    mfma_half(7);

    // ---- epilogue: C/D col = mrow (pixel), row = quad*4 + jj (cout) ----
    const int wo = wt + mrow;
    if (wo < WO) {
        const size_t outb = (size_t)b * (COUT * HW_) + (size_t)(ho * WO + wo);
        #pragma unroll
        for (int jj = 0; jj < 4; ++jj) {
            int o0 = blk0 * 16 + quad * 4 + jj;
            int o1 = blk1 * 16 + quad * 4 + jj;
            out[outb + (size_t)o0 * HW_] = acc0[jj] + bias[o0];
            out[outb + (size_t)o1 * HW_] = acc1[jj] + bias[o1];
        }
    }
}

extern "C" void kernel_launch(void* const* d_in, const int* in_sizes, int n_in,
                              void* d_out, int out_size, void* d_ws, size_t ws_size,
                              hipStream_t stream) {
    const float* inp  = (const float*)d_in[0];
    const float* off  = (const float*)d_in[1];
    const float* msk  = (const float*)d_in[2];
    const float* wgt  = (const float*)d_in[3];
    const float* bias = (const float*)d_in[4];
    float* out = (float*)d_out;

    __hip_bfloat16* A2 = (__hip_bfloat16*)d_ws;                 // 512 KB
    float* T = (float*)((char*)d_ws + (1 << 20));               // 16 MB

    transpose_in<<<512, 256, 0, stream>>>(inp, T);
    prep_weight<<<128, 256, 0, stream>>>(wgt, A2);

    int nblk = B_ * HO * 4;                // 1952, bid&7 = batch
    deform_gather<<<nblk, 256, 0, stream>>>(T, off, msk, A2, bias, out);
}

// Round 5
// 134.003 us; speedup vs baseline: 1.8029x; 1.2954x over previous
//
#include <hip/hip_runtime.h>
#include <hip/hip_bf16.h>

// Problem constants
#define B_    8
#define CIN   128
#define H_    64
#define W_    64
#define COUT  128
#define K_    16
#define HO    61
#define WO    61
#define HW_   (HO * WO)          // 3721

typedef short bf16x8 __attribute__((ext_vector_type(8)));
typedef short s16x4  __attribute__((ext_vector_type(4)));
typedef float f32x4  __attribute__((ext_vector_type(4)));
typedef float f32x4u __attribute__((ext_vector_type(4), aligned(4)));

#define B2F(s) __uint_as_float(((unsigned int)(unsigned short)(s)) << 16)

// ---------------------------------------------------------------------------
// Fused prep: blocks 0..511 transpose input [b][c][y][x] f32 -> T[b][y*64+x][c]
// bf16 (1 MB/batch, XCD-L2 resident); blocks 512..639 repack weight.
// Weight layout (fragment-major, pre-flipped, kk = k*128 + c):
//   A2[((blk*64 + it)*64 + lane)*8 + j];  o = blk*16 + (lane&15);
//   kk = it*32 + (lane>>4)*8 + j;  k = kk>>7;  c = kk&127.
__global__ __launch_bounds__(256) void prep_all(const float* __restrict__ inp,
                                                const float* __restrict__ w,
                                                __hip_bfloat16* __restrict__ T,
                                                __hip_bfloat16* __restrict__ A2) {
    const int t = threadIdx.x;
    if (blockIdx.x < 512) {
        __shared__ float ld[64][129];      // pad 129: conflict-free both phases
        const int b  = blockIdx.x >> 6;
        const int sb = (blockIdx.x & 63) << 6;   // 64-spatial slab
        const float* src = inp + ((size_t)b << 19);
        #pragma unroll
        for (int i = 0; i < 8; ++i) {
            int j  = i * 256 + t;
            int c  = j >> 4;
            int s4 = (j & 15) << 2;
            f32x4u v = *(const f32x4u*)(const void*)(src + ((size_t)c << 12) + sb + s4);
            #pragma unroll
            for (int q = 0; q < 4; ++q) ld[s4 + q][c] = v[q];
        }
        __syncthreads();
        __hip_bfloat16* dst = T + (((size_t)b << 12) + sb) * 128;
        #pragma unroll
        for (int i = 0; i < 8; ++i) {
            int j  = i * 256 + t;
            int s  = j >> 5;
            int c4 = (j & 31) << 2;
            s16x4 v;
            #pragma unroll
            for (int q = 0; q < 4; ++q) {
                __hip_bfloat16 hh = __float2bfloat16(ld[s][c4 + q]);
                v[q] = *reinterpret_cast<const short*>(&hh);
            }
            *(s16x4*)(void*)(dst + (size_t)s * 128 + c4) = v;
        }
    } else {
        int gid  = (blockIdx.x - 512) * 256 + t;   // 32768 threads
        int lane = gid & 63;
        int it   = (gid >> 6) & 63;
        int blk  = gid >> 12;
        int o    = blk * 16 + (lane & 15);
        int kk   = it * 32 + (lane >> 4) * 8;      // never crosses c=128
        int k    = kk >> 7;
        int c0   = kk & 127;
        const float* srcw = w + (((size_t)(o << 7) + c0) << 4) + (15 - k);
        __hip_bfloat16* dst = A2 + (size_t)gid * 8;
        #pragma unroll
        for (int j = 0; j < 8; ++j)
            dst[j] = __float2bfloat16(srcw[j << 4]);   // c = c0+j, same k
    }
}

// ---------------------------------------------------------------------------
// Main: block = 16 pixels x 128 couts, 4 waves.  bf16 channel-last gather
// (unit = 1 tap x 32 ch x 16 pixels; 4 dwordx4/lane, one 64B line per
// pair-corner) -> swizzled Bs ring -> MFMA with A-fragments HOISTED into regs
// and issued FIRST in the vmem queue each half, so counted vmcnt releases the
// MFMA without draining the gather loads.  9 barriers/block.
__global__ __launch_bounds__(256, 3) void deform_gather(
        const __hip_bfloat16* __restrict__ T, const float* __restrict__ off,
        const float* __restrict__ msk, const __hip_bfloat16* __restrict__ A2,
        const float* __restrict__ bias, float* __restrict__ out) {

    __shared__ __align__(16) __hip_bfloat16 Bs[2][16 * 256];  // 2 x 8 KB
    __shared__ float pw[4][256];                              // b00,b01,b10,b11
    __shared__ int   pb[2][256];                              // T elem offsets

    const int t   = threadIdx.x;
    const int bid = blockIdx.x;
    const int b   = bid & 7;               // batch<->XCD pinning
    const int g   = bid >> 3;
    const int ho  = g >> 2;
    const int wt  = (g & 3) << 4;

    // ---- phase 0: exact per-(pixel,tap) bilinear params -> LDS ----
    {
        const int p  = t & 15;
        const int k  = t >> 4;
        const int wo = wt + p;
        const bool pvalid = (wo < WO);
        const int wo_c = pvalid ? wo : (WO - 1);
        const int r    = ho * WO + wo_c;
        const int ki = k >> 2, kj = k & 3;
        const size_t offb = (size_t)b * (2 * K_ * HW_);
        float dy = off[offb + (size_t)(2 * k)     * HW_ + r];
        float dx = off[offb + (size_t)(2 * k + 1) * HW_ + r];
        float mm = msk[(size_t)b * (K_ * HW_) + (size_t)k * HW_ + r];
        if (!pvalid) mm = 0.0f;

        float y   = dy + (float)(ki + ho);
        float x   = dx + (float)(kj + wo_c);
        float y0f = floorf(y), x0f = floorf(x);
        float wy  = y - y0f,   wx  = x - x0f;
        int y0 = (int)y0f, x0 = (int)x0f;
        int y1 = y0 + 1,   x1 = x0 + 1;

        float wy0v = (1.0f - wy) * ((y0 >= 0 && y0 < H_) ? mm : 0.0f);
        float wy1v = wy          * ((y1 >= 0 && y1 < H_) ? mm : 0.0f);
        int cy0 = min(max(y0, 0), H_ - 1), cy1 = min(max(y1, 0), H_ - 1);

        float wx0v = (1.0f - wx) * ((x0 >= 0 && x0 < W_) ? 1.0f : 0.0f);
        float wx1v = wx          * ((x1 >= 0 && x1 < W_) ? 1.0f : 0.0f);
        int xb = min(max(x0, 0), W_ - 2);
        int tsh = x0 - xb;                 // -1,0,1 (else both x-weights 0)
        float a0 = (tsh == 0) ? wx0v : ((tsh == -1) ? wx1v : 0.0f);
        float a1 = (tsh == 0) ? wx1v : ((tsh ==  1) ? wx0v : 0.0f);

        pw[0][t] = wy0v * a0;  pw[1][t] = wy0v * a1;
        pw[2][t] = wy1v * a0;  pw[3][t] = wy1v * a1;
        pb[0][t] = (cy0 * W_ + xb) << 7;   // *128 channels
        pb[1][t] = (cy1 * W_ + xb) << 7;
    }
    __syncthreads();

    const int lane = t & 63;
    const int wv   = t >> 6;
    const int p_g  = lane >> 2;            // gather pixel (16 pairs/wave)
    const int cg_l = (lane & 3) << 3;      // 8-ch sub-slice within 32-group
    const int mrow = lane & 15;            // MFMA pixel col
    const int quad = lane >> 4;
    const __hip_bfloat16* Tb = T + ((size_t)b << 19);
    const int u0 = wv, u1 = wv + 4;        // this wave's 2 units per half
    const int blk0 = 2 * wv, blk1 = 2 * wv + 1;

    f32x4 acc0 = {0.f, 0.f, 0.f, 0.f};
    f32x4 acc1 = {0.f, 0.f, 0.f, 0.f};

    // unit gather: 4 coalesced dwordx4 (one per corner, 8 bf16 ch each).
    // Corner order: cv[0]=(y0,x0) cv[1]=(y0,x1) cv[2]=(y1,x0) cv[3]=(y1,x1)
    auto uget = [&](int u, int h, bf16x8* cv, float* wts, int& swz) {
        const int tap  = 2 * h + (u >> 2);
        const int pair = (tap << 4) + p_g;
        wts[0] = pw[0][pair]; wts[1] = pw[1][pair];
        wts[2] = pw[2][pair]; wts[3] = pw[3][pair];
        const int cb = ((u & 3) << 5) + cg_l;
        const __hip_bfloat16* p0 = Tb + pb[0][pair] + cb;
        const __hip_bfloat16* p1 = Tb + pb[1][pair] + cb;
        cv[0] = *(const bf16x8*)(const void*)(p0);
        cv[1] = *(const bf16x8*)(const void*)(p0 + 128);   // x+1 pixel
        cv[2] = *(const bf16x8*)(const void*)(p1);
        cv[3] = *(const bf16x8*)(const void*)(p1 + 128);
        const int kkl = ((u >> 2) << 7) + cb;              // local kk base
        swz = (p_g << 8) + ((kkl + (p_g << 3)) & 255);
    };

    // combine (bf16 corners -> f32 bilinear -> bf16) -> one ds_write_b128
    auto ucombine = [&](const bf16x8* cv, const float* wts, int swz, int hb) {
        bf16x8 bb;
        #pragma unroll
        for (int q = 0; q < 8; ++q) {
            float s = wts[0] * B2F(cv[0][q]) + wts[1] * B2F(cv[1][q])
                    + wts[2] * B2F(cv[2][q]) + wts[3] * B2F(cv[3][q]);
            __hip_bfloat16 hh = __float2bfloat16(s);
            bb[q] = *reinterpret_cast<const short*>(&hh);
        }
        *(bf16x8*)(void*)(&Bs[hb][swz]) = bb;
    };

    // A-fragments for one half, held in registers (16 x bf16x8 = 64 VGPR)
    bf16x8 avR[16];
    auto loadA = [&](int hp) {
        const __hip_bfloat16* a0 = A2 + ((size_t)((blk0 * 64 + hp * 8) * 64 + lane) << 3);
        const __hip_bfloat16* a1 = A2 + ((size_t)((blk1 * 64 + hp * 8) * 64 + lane) << 3);
        #pragma unroll
        for (int s_ = 0; s_ < 8; ++s_) {
            avR[2 * s_]     = *(const bf16x8*)(const void*)(a0 + ((size_t)s_ << 9));
            avR[2 * s_ + 1] = *(const bf16x8*)(const void*)(a1 + ((size_t)s_ << 9));
        }
    };
    auto mfma_exec = [&](int hp) {
        const int hb = hp & 1;
        #pragma unroll
        for (int s_ = 0; s_ < 8; ++s_) {
            const int idx = (mrow << 8) +
                            (((s_ << 5) + (quad << 3) + (mrow << 3)) & 255);
            bf16x8 bb = *(const bf16x8*)(const void*)(&Bs[hb][idx]);
            acc0 = __builtin_amdgcn_mfma_f32_16x16x32_bf16(avR[2 * s_],     bb, acc0, 0, 0, 0);
            acc1 = __builtin_amdgcn_mfma_f32_16x16x32_bf16(avR[2 * s_ + 1], bb, acc1, 0, 0, 0);
        }
    };

    bf16x8 cU0[4], cU1[4];
    float  wt0[4], wt1[4];
    int    sw0, sw1;

    // prologue: half 0
    uget(u0, 0, cU0, wt0, sw0);
    uget(u1, 0, cU1, wt1, sw1);
    ucombine(cU0, wt0, sw0, 0);
    ucombine(cU1, wt1, sw1, 0);
    __syncthreads();

    #pragma unroll 1
    for (int h = 1; h < 8; ++h) {
        loadA(h - 1);                      // A-loads FIRST in vmem queue
        uget(u0, h, cU0, wt0, sw0);        // gather loads behind them
        uget(u1, h, cU1, wt1, sw1);
        __builtin_amdgcn_s_setprio(1);
        mfma_exec(h - 1);                  // waits only on A (oldest in queue)
        __builtin_amdgcn_s_setprio(0);
        ucombine(cU0, wt0, sw0, h & 1);    // waits gathers (covered by MFMA)
        ucombine(cU1, wt1, sw1, h & 1);
        __syncthreads();                   // one barrier per half
    }
    loadA(7);
    mfma_exec(7);

    // ---- epilogue: C/D col = mrow (pixel), row = quad*4 + jj (cout) ----
    const int wo = wt + mrow;
    if (wo < WO) {
        const size_t outb = (size_t)b * (COUT * HW_) + (size_t)(ho * WO + wo);
        #pragma unroll
        for (int jj = 0; jj < 4; ++jj) {
            int o0 = blk0 * 16 + quad * 4 + jj;
            int o1 = blk1 * 16 + quad * 4 + jj;
            out[outb + (size_t)o0 * HW_] = acc0[jj] + bias[o0];
            out[outb + (size_t)o1 * HW_] = acc1[jj] + bias[o1];
        }
    }
}

extern "C" void kernel_launch(void* const* d_in, const int* in_sizes, int n_in,
                              void* d_out, int out_size, void* d_ws, size_t ws_size,
                              hipStream_t stream) {
    const float* inp  = (const float*)d_in[0];
    const float* off  = (const float*)d_in[1];
    const float* msk  = (const float*)d_in[2];
    const float* wgt  = (const float*)d_in[3];
    const float* bias = (const float*)d_in[4];
    float* out = (float*)d_out;

    __hip_bfloat16* A2 = (__hip_bfloat16*)d_ws;                       // 512 KB
    __hip_bfloat16* T  = (__hip_bfloat16*)((char*)d_ws + (1 << 20));  // 8 MB

    prep_all<<<640, 256, 0, stream>>>(inp, wgt, T, A2);

    int nblk = B_ * HO * 4;                // 1952, bid&7 = batch
    deform_gather<<<nblk, 256, 0, stream>>>(T, off, msk, A2, bias, out);
}